// Round 1
// baseline (106.689 us; speedup 1.0000x reference)
//
#include <hip/hip_runtime.h>
#include <hip/hip_bf16.h>

// VDEmbedding: out[t, :] = mask[x[t]] * weight[x[t], :], zero at x==PAD_IDX(0).
// Pure gather, memory-bound. 32 lanes/token, float4 (16B) per lane -> one
// 512B row per 32-lane group, fully coalesced writes.

#define TOKENS (16 * 4096)
#define EMBED_DIM 128
#define LANES_PER_TOKEN 32          // EMBED_DIM / 4 floats per float4
#define PAD_IDX 0

__global__ __launch_bounds__(256) void vdemb_gather_kernel(
    const int* __restrict__ x,        // [TOKENS] indices
    const float4* __restrict__ w4,    // [VOCAB * 32] weight as float4
    const float* __restrict__ mask,   // [VOCAB]
    float4* __restrict__ out4)        // [TOKENS * 32]
{
    const int tid   = blockIdx.x * blockDim.x + threadIdx.x;
    const int token = tid >> 5;       // 32 lanes per token
    const int lane  = tid & 31;
    if (token >= TOKENS) return;

    const int idx = x[token];
    // weight[PAD_IDX] is all-zero and reference zeroes pad rows; force scale=0
    // at pad for exact semantics regardless of mask[0].
    const float scale = (idx == PAD_IDX) ? 0.0f : mask[idx];

    const float4 w = w4[(size_t)idx * LANES_PER_TOKEN + lane];
    float4 o;
    o.x = w.x * scale;
    o.y = w.y * scale;
    o.z = w.z * scale;
    o.w = w.w * scale;
    out4[(size_t)token * LANES_PER_TOKEN + lane] = o;
}

extern "C" void kernel_launch(void* const* d_in, const int* in_sizes, int n_in,
                              void* d_out, int out_size, void* d_ws, size_t ws_size,
                              hipStream_t stream) {
    const int*    x    = (const int*)d_in[0];     // [16*4096]
    const float4* w4   = (const float4*)d_in[1];  // [128000, 128] fp32 as float4
    const float*  mask = (const float*)d_in[2];   // [128000]
    float4*       out4 = (float4*)d_out;          // [16*4096*128] fp32 as float4

    const int total_threads = TOKENS * LANES_PER_TOKEN;  // 2,097,152
    const int block = 256;
    const int grid  = (total_threads + block - 1) / block;  // 8192
    vdemb_gather_kernel<<<grid, block, 0, stream>>>(x, w4, mask, out4);
}